// Round 10
// baseline (231.245 us; speedup 1.0000x reference)
//
#include <hip/hip_runtime.h>
#include <hip/hip_bf16.h>

#define T_SEQ 4096
#define C_EMB 768
#define HEAD  64

typedef short  short8  __attribute__((ext_vector_type(8)));
typedef float  floatx4 __attribute__((ext_vector_type(4)));

static __device__ __forceinline__ short f2bf(float v) {
    __hip_bfloat16 h = __float2bfloat16(v);
    return *reinterpret_cast<short*>(&h);
}
static __device__ __forceinline__ float bf2f(short s) {
    unsigned u = ((unsigned)(unsigned short)s) << 16;
    return __uint_as_float(u);
}

// ---------------------------------------------------------------------------
// Kernel 0: transpose+downcast fp32 W[768][64] -> bf16 Wt[g][n=64][k=768]
// ---------------------------------------------------------------------------
__global__ void wt_transpose_kernel(const float* __restrict__ Wk,
                                    const float* __restrict__ Wq,
                                    const float* __restrict__ Wv,
                                    short* __restrict__ Wt) {
    const int total = 3 * HEAD * C_EMB;
    for (int idx = blockIdx.x * blockDim.x + threadIdx.x; idx < total;
         idx += gridDim.x * blockDim.x) {
        int g   = idx / (HEAD * C_EMB);
        int rem = idx - g * (HEAD * C_EMB);
        int n   = rem / C_EMB;
        int k   = rem - n * C_EMB;
        const float* W = (g == 0) ? Wk : (g == 1) ? Wq : Wv;
        Wt[idx] = f2bf(W[k * HEAD + n]);
    }
}

// ---------------------------------------------------------------------------
// Kernel 1: QKV via MFMA, 256 blocks x 768 thr (12 waves), 1-deep prefetch.
// wave = (g = wave>>2, rowgrp = wave&3); wave does 16 rows x 64 cols of one
// output. K is stored PRESCALED by 768^-0.5*log2(e) (bias included).
// ---------------------------------------------------------------------------
__global__ __launch_bounds__(768) void qkv_mfma(
    const float* __restrict__ x, const short* __restrict__ Wt,
    const float* __restrict__ bk, const float* __restrict__ bq,
    const float* __restrict__ bv,
    short* __restrict__ Kb, short* __restrict__ Qb, short* __restrict__ Vt) {
    const float scale2 = 0.052058773f;   // 768^-0.5 * log2(e)
    int tid  = threadIdx.x;
    int wave = tid >> 6, lane = tid & 63;
    int ln15 = lane & 15, quad = lane >> 4;
    int g = wave >> 2, rowgrp = wave & 3;
    int row = blockIdx.x * 64 + rowgrp * 16 + ln15;   // A-frag row (m=lane&15)

    floatx4 acc[4];
#pragma unroll
    for (int j = 0; j < 4; ++j) acc[j] = (floatx4){0.f, 0.f, 0.f, 0.f};

    const float* xrow = x + (size_t)row * C_EMB + quad * 8;
    const short* wrow[4];
#pragma unroll
    for (int j = 0; j < 4; ++j)
        wrow[j] = Wt + ((size_t)(g * HEAD + j * 16 + ln15)) * C_EMB + quad * 8;

    floatx4 f0 = *(const floatx4*)(xrow);
    floatx4 f1 = *(const floatx4*)(xrow + 4);
    short8 wf[4];
#pragma unroll
    for (int j = 0; j < 4; ++j) wf[j] = *(const short8*)(wrow[j]);

    for (int kc = 0; kc < 24; ++kc) {
        short8 a;
#pragma unroll
        for (int e = 0; e < 4; ++e) { a[e] = f2bf(f0[e]); a[4 + e] = f2bf(f1[e]); }
        int nk = (kc < 23) ? (kc + 1) * 32 : kc * 32;   // clamped prefetch
        floatx4 nf0 = *(const floatx4*)(xrow + nk);
        floatx4 nf1 = *(const floatx4*)(xrow + nk + 4);
        short8 nwf[4];
#pragma unroll
        for (int j = 0; j < 4; ++j) nwf[j] = *(const short8*)(wrow[j] + nk);
#pragma unroll
        for (int j = 0; j < 4; ++j)
            acc[j] = __builtin_amdgcn_mfma_f32_16x16x32_bf16(a, wf[j], acc[j], 0, 0, 0);
        f0 = nf0; f1 = nf1;
#pragma unroll
        for (int j = 0; j < 4; ++j) wf[j] = nwf[j];
    }

    const float* bp = (g == 0) ? bk : (g == 1) ? bq : bv;
#pragma unroll
    for (int j = 0; j < 4; ++j) {
        int nl = j * 16 + ln15;
        float bias = bp[nl];
#pragma unroll
        for (int r = 0; r < 4; ++r) {
            int grow = blockIdx.x * 64 + rowgrp * 16 + quad * 4 + r;  // C/D row
            float v = acc[j][r] + bias;
            if (g == 0)      Kb[(size_t)grow * HEAD + nl] = f2bf(v * scale2);
            else if (g == 1) Qb[(size_t)grow * HEAD + nl] = f2bf(v);
            else {
                int b = grow >> 12, t = grow & 4095;
                Vt[((size_t)(b * HEAD + nl) << 12) + t] = f2bf(v);  // V transposed
            }
        }
    }
}

// ---------------------------------------------------------------------------
// Kernel 2: causal flash attention partial — ONE WAVE per block, no barriers,
// Q/V fragments straight from global (L1/L2-hot), softmax without running
// max (scores bounded; scale pre-folded into K). Block handles 16 t-rows x
// one s-chunk (<=32 s-tiles). Partials: raw sums O (bf16) and l (fp32).
// grid.x = 384: bx<256 -> (g16=bx, c=0); else (g16=128+bx-256, c=1).
// ---------------------------------------------------------------------------
__global__ __launch_bounds__(64) void attn_part(
    const short* __restrict__ Kb, const short* __restrict__ Qb,
    const short* __restrict__ Vt, short* __restrict__ Opart,
    float* __restrict__ lpart) {
    __shared__ __align__(16) short Ps[16][72];   // wave-local P round-trip

    int lane = threadIdx.x;
    int ln15 = lane & 15, quad = lane >> 4;
    int bx = blockIdx.x, b = blockIdx.y;
    int g16 = (bx < 256) ? bx : 128 + (bx - 256);
    int c   = (bx < 256) ? 0 : 1;
    int dtile = g16 >> 2;                 // diagonal s-tile index
    int lo = c * 32;
    int hi = min(dtile, c * 32 + 31);

    // K A-fragments (prescaled) for this wave's 16 t-rows
    const short* kp = Kb + ((size_t)(b * T_SEQ + g16 * 16 + ln15)) * HEAD + quad * 8;
    short8 ak0 = *(const short8*)kp;
    short8 ak1 = *(const short8*)(kp + 32);

    floatx4 o[4];
#pragma unroll
    for (int j = 0; j < 4; ++j) o[j] = (floatx4){0.f, 0.f, 0.f, 0.f};
    float lsum[4] = {0.f, 0.f, 0.f, 0.f};

    // per-lane global pointers (advance per s-tile)
    const short* qp = Qb + ((size_t)(b * T_SEQ + lo * 64) + ln15) * HEAD + quad * 8;
    const short* vp = Vt + (((size_t)(b * HEAD + ln15)) << 12) + lo * 64 + quad * 8;

    for (int st = lo; st <= hi; ++st) {
        // Q B-frags: n = s0+nb*16+ln15, k = h = quad*8+j (+32)
        short8 bq0[4], bq1[4];
#pragma unroll
        for (int nb = 0; nb < 4; ++nb) {
            bq0[nb] = *(const short8*)(qp + nb * 16 * HEAD);
            bq1[nb] = *(const short8*)(qp + nb * 16 * HEAD + 32);
        }
        // V B-frags (issue early): n = h = j*16+ln15, k = s0+quad*8+jj (+32)
        short8 bv0[4], bv1[4];
#pragma unroll
        for (int j = 0; j < 4; ++j) {
            bv0[j] = *(const short8*)(vp + ((size_t)j << 16));
            bv1[j] = *(const short8*)(vp + ((size_t)j << 16) + 32);
        }

        // S = K' . Q^T   (already includes scale*log2e)
        floatx4 sacc[4];
#pragma unroll
        for (int nb = 0; nb < 4; ++nb) {
            floatx4 z4 = (floatx4){0.f, 0.f, 0.f, 0.f};
            z4 = __builtin_amdgcn_mfma_f32_16x16x32_bf16(ak0, bq0[nb], z4, 0, 0, 0);
            z4 = __builtin_amdgcn_mfma_f32_16x16x32_bf16(ak1, bq1[nb], z4, 0, 0, 0);
            sacc[nb] = z4;
        }

        // p = exp2(z), no max subtraction (z bounded); accumulate l; pack P
        if (st == dtile) {
            int s0 = st * 64;
#pragma unroll
            for (int r = 0; r < 4; ++r) {
                int tg = g16 * 16 + quad * 4 + r;
#pragma unroll
                for (int nb = 0; nb < 4; ++nb) {
                    int sg = s0 + nb * 16 + ln15;
                    float pv = exp2f(sacc[nb][r]);
                    pv = (sg > tg) ? 0.f : pv;
                    lsum[r] += pv;
                    Ps[quad * 4 + r][nb * 16 + ln15] = f2bf(pv);
                }
            }
        } else {
#pragma unroll
            for (int r = 0; r < 4; ++r) {
#pragma unroll
                for (int nb = 0; nb < 4; ++nb) {
                    float pv = exp2f(sacc[nb][r]);
                    lsum[r] += pv;
                    Ps[quad * 4 + r][nb * 16 + ln15] = f2bf(pv);
                }
            }
        }
        __asm__ volatile("s_waitcnt lgkmcnt(0)" ::: "memory");
        short8 ap0 = *(const short8*)&Ps[ln15][quad * 8];
        short8 ap1 = *(const short8*)&Ps[ln15][32 + quad * 8];

        // O += P . V
#pragma unroll
        for (int j = 0; j < 4; ++j) {
            o[j] = __builtin_amdgcn_mfma_f32_16x16x32_bf16(ap0, bv0[j], o[j], 0, 0, 0);
            o[j] = __builtin_amdgcn_mfma_f32_16x16x32_bf16(ap1, bv1[j], o[j], 0, 0, 0);
        }

        qp += 64 * HEAD;   // next s-tile rows
        vp += 64;          // next 64 t-positions
    }

    // one-time l reduction across the 16 n-lanes
#pragma unroll
    for (int mask = 1; mask <= 8; mask <<= 1) {
#pragma unroll
        for (int r = 0; r < 4; ++r)
            lsum[r] += __shfl_xor(lsum[r], mask, 64);
    }

    // store partials
#pragma unroll
    for (int r = 0; r < 4; ++r) {
        int t = g16 * 16 + quad * 4 + r;
        size_t rowidx = ((size_t)(c * 4 + b)) * T_SEQ + t;
        if (ln15 == 0) lpart[rowidx] = lsum[r];
#pragma unroll
        for (int j = 0; j < 4; ++j)
            Opart[rowidx * HEAD + j * 16 + ln15] = f2bf(o[j][r]);
    }
}

// ---------------------------------------------------------------------------
// Kernel 3: merge <=2 partials per row (exact addition: no per-chunk max).
// ---------------------------------------------------------------------------
__global__ __launch_bounds__(256) void attn_merge(
    const short* __restrict__ Opart, const float* __restrict__ lpart,
    float* __restrict__ out) {
    int idx = blockIdx.x * 256 + threadIdx.x;       // 0 .. 1048575
    int tg = idx >> 6, h = idx & 63;
    int b = tg >> 12, t = tg & 4095;
    size_t r0 = ((size_t)b) * T_SEQ + t;
    float l = lpart[r0];
    float o = bf2f(Opart[r0 * HEAD + h]);
    if ((t >> 6) >= 32) {                            // chunk 1 exists
        size_t r1 = ((size_t)(4 + b)) * T_SEQ + t;
        l += lpart[r1];
        o += bf2f(Opart[r1 * HEAD + h]);
    }
    out[idx] = o / l;
}

extern "C" void kernel_launch(void* const* d_in, const int* in_sizes, int n_in,
                              void* d_out, int out_size, void* d_ws, size_t ws_size,
                              hipStream_t stream) {
    // Size-based input mapping (order-robust; W's and b's keep internal order)
    const int XSZ = 4 * T_SEQ * C_EMB;   // 12582912
    const int WSZ = C_EMB * HEAD;        // 49152
    const int BSZ = HEAD;                // 64
    const float* x = nullptr;
    const float* W[3] = {nullptr, nullptr, nullptr};
    const float* B[3] = {nullptr, nullptr, nullptr};
    int iw = 0, ib = 0;
    for (int i = 0; i < n_in; ++i) {
        if (in_sizes[i] == XSZ) x = (const float*)d_in[i];
        else if (in_sizes[i] == WSZ && iw < 3) W[iw++] = (const float*)d_in[i];
        else if (in_sizes[i] == BSZ && ib < 3) B[ib++] = (const float*)d_in[i];
    }

    short* ws = (short*)d_ws;
    short* Kb = ws;                               // [16384][64] bf16   2 MB
    short* Qb = Kb + (size_t)4 * T_SEQ * HEAD;    // [16384][64] bf16   2 MB
    short* Vt = Qb + (size_t)4 * T_SEQ * HEAD;    // [4][64][4096] bf16 2 MB
    short* Wt = Vt + (size_t)4 * HEAD * T_SEQ;    // [3][64][768] bf16  288 KB
    short* Opart = Wt + (size_t)3 * HEAD * C_EMB; // [2][4][4096][64]   4 MB
    float* lpart = (float*)(Opart + (size_t)2 * 4 * T_SEQ * HEAD); // 128 KB

    wt_transpose_kernel<<<96, 256, 0, stream>>>(W[0], W[1], W[2], Wt);
    qkv_mfma<<<256, 768, 0, stream>>>(x, Wt, B[0], B[1], B[2], Kb, Qb, Vt);
    attn_part<<<dim3(384, 4), 64, 0, stream>>>(Kb, Qb, Vt, Opart, lpart);
    attn_merge<<<4096, 256, 0, stream>>>(Opart, lpart, (float*)d_out);
}